// Round 1
// baseline (329.212 us; speedup 1.0000x reference)
//
#include <hip/hip_runtime.h>

// Problem constants (from reference setup_inputs)
constexpr int kB = 16, kQ = 900, kC = 91, kT = 4800;
constexpr int kBQ = kB * kQ;          // 14400
constexpr int kTI = 16;               // queries per block (blockIdx.y tile)

// ---------------------------------------------------------------------------
// Kernel A: precompute weighted focal class-cost table cd[BQ, C]
//   cd = W_CLASS * (pos_cost - neg_cost)
// ---------------------------------------------------------------------------
__global__ __launch_bounds__(256)
void class_cost_kernel(const float* __restrict__ logits,
                       float* __restrict__ cd, int n) {
    int idx = blockIdx.x * 256 + threadIdx.x;
    if (idx >= n) return;
    float x = logits[idx];
    float p = 1.0f / (1.0f + expf(-x));          // sigmoid, fp32 like ref
    float omp = 1.0f - p;
    float pos = 0.25f * omp * omp * (-logf(p + 1e-8f));
    float neg = 0.75f * p * p * (-logf(omp + 1e-8f));
    cd[idx] = 2.0f * (pos - neg);                // W_CLASS folded in
}

// ---------------------------------------------------------------------------
// Kernel B: full cost matrix out[BQ, T]
//   grid = (ceil(T/256), BQ/16), block = 256
//   thread owns one target j (converted once), loops over 16 queries i.
// ---------------------------------------------------------------------------
__global__ __launch_bounds__(256)
void cost_kernel(const float* __restrict__ pred_boxes,   // [BQ,4] cxcywh
                 const int*   __restrict__ tgt_ids,      // [T] 1-based
                 const float* __restrict__ tgt_boxes,    // [T,4] cxcywh
                 const float* __restrict__ cd,           // [BQ,C] weighted
                 float*       __restrict__ out) {        // [BQ,T]
    const int j  = blockIdx.x * 256 + threadIdx.x;
    const int i0 = blockIdx.y * kTI;
    const bool valid = (j < kT);

    // Per-thread target data: load + convert ONCE (reused across 16 i's)
    float tcx = 0.f, tcy = 0.f, tw = 0.f, th = 0.f;
    float tx0 = 0.f, ty0 = 0.f, tx1 = 0.f, ty1 = 0.f, ta = 0.f;
    int tc = 0;
    if (valid) {
        float4 tb = reinterpret_cast<const float4*>(tgt_boxes)[j];
        tcx = tb.x; tcy = tb.y; tw = tb.z; th = tb.w;
        tx0 = tcx - 0.5f * tw;  ty0 = tcy - 0.5f * th;
        tx1 = tcx + 0.5f * tw;  ty1 = tcy + 0.5f * th;
        ta  = tw * th;
        tc  = tgt_ids[j] - 1;                    // 0..90
    }

    for (int ii = 0; ii < kTI; ++ii) {
        const int i = i0 + ii;
        // Uniform per-iteration load (same addr across block -> scalar/L1)
        float4 pb = reinterpret_cast<const float4*>(pred_boxes)[i];
        float pcx = pb.x, pcy = pb.y, pw = pb.z, ph = pb.w;
        float px0 = pcx - 0.5f * pw, py0 = pcy - 0.5f * ph;
        float px1 = pcx + 0.5f * pw, py1 = pcy + 0.5f * ph;
        float pa  = pw * ph;

        float cdv = valid ? cd[i * kC + tc] : 0.f;   // gather, L1-resident row

        // L1 cost in cxcywh space
        float l1 = fabsf(pcx - tcx) + fabsf(pcy - tcy)
                 + fabsf(pw  - tw ) + fabsf(ph  - th );

        // intersection
        float lx = fmaxf(px0, tx0), ly = fmaxf(py0, ty0);
        float rx = fminf(px1, tx1), ry = fminf(py1, ty1);
        float iw = fmaxf(rx - lx, 0.f), ih = fmaxf(ry - ly, 0.f);
        float inter = iw * ih;
        float uni   = pa + ta - inter;
        float iou   = inter * __builtin_amdgcn_rcpf(fmaxf(uni, 1e-6f));

        // enclosing box
        float ex0 = fminf(px0, tx0), ey0 = fminf(py0, ty0);
        float ex1 = fmaxf(px1, tx1), ey1 = fmaxf(py1, ty1);
        float ew  = fmaxf(ex1 - ex0, 0.f), eh = fmaxf(ey1 - ey0, 0.f);
        float enc = ew * eh;
        float giou = iou - (enc - uni) * __builtin_amdgcn_rcpf(fmaxf(enc, 1e-6f));

        // cd already carries W_CLASS=2; W_BBOX=5, W_GIOU=2 (cost is -giou)
        float cost = cdv + 5.0f * l1 - 2.0f * giou;

        if (valid) out[(size_t)i * kT + j] = cost;
    }
}

extern "C" void kernel_launch(void* const* d_in, const int* in_sizes, int n_in,
                              void* d_out, int out_size, void* d_ws, size_t ws_size,
                              hipStream_t stream) {
    const float* logits  = (const float*)d_in[0];   // [16,900,91]
    const float* pboxes  = (const float*)d_in[1];   // [16,900,4]
    const int*   tids    = (const int*)d_in[2];     // [4800]
    const float* tboxes  = (const float*)d_in[3];   // [4800,4]
    float* out = (float*)d_out;                     // [16,900,4800]
    float* cd  = (float*)d_ws;                      // [14400,91] = 5.24 MB

    const int n_cd = kBQ * kC;
    class_cost_kernel<<<(n_cd + 255) / 256, 256, 0, stream>>>(logits, cd, n_cd);

    dim3 grid((kT + 255) / 256, kBQ / kTI);         // (19, 900)
    cost_kernel<<<grid, 256, 0, stream>>>(pboxes, tids, tboxes, cd, out);
}

// Round 2
// 316.013 us; speedup vs baseline: 1.0418x; 1.0418x over previous
//
#include <hip/hip_runtime.h>

// Problem constants (from reference setup_inputs)
constexpr int kB = 16, kQ = 900, kC = 91, kT = 4800;
constexpr int kBQ = kB * kQ;          // 14400
constexpr int kTI = 16;               // queries (i rows) per block
constexpr int kJT = 4;                // targets (j) per thread -> dwordx4 stores
constexpr int kBT = 256;              // threads per block
constexpr int kJB = kBT * kJT;        // 1024 j per block

// ---------------------------------------------------------------------------
// Kernel A: precompute weighted focal class-cost table cd[BQ, C]
//   cd = W_CLASS * (pos_cost - neg_cost)
// ---------------------------------------------------------------------------
__global__ __launch_bounds__(256)
void class_cost_kernel(const float* __restrict__ logits,
                       float* __restrict__ cd, int n) {
    int idx = blockIdx.x * 256 + threadIdx.x;
    if (idx >= n) return;
    float x = logits[idx];
    float p = 1.0f / (1.0f + expf(-x));          // sigmoid, fp32 like ref
    float omp = 1.0f - p;
    float pos = 0.25f * omp * omp * (-logf(p + 1e-8f));
    float neg = 0.75f * p * p * (-logf(omp + 1e-8f));
    cd[idx] = 2.0f * (pos - neg);                // W_CLASS folded in
}

// ---------------------------------------------------------------------------
// Kernel B: cost matrix out[BQ, T]
//   grid = (ceil(T/1024), BQ/16), block = 256
//   thread owns 4 consecutive j (one dwordx4 store per i), loops 16 i's.
//   cd rows + pred boxes staged in LDS once per block.
// ---------------------------------------------------------------------------
__global__ __launch_bounds__(256)
void cost_kernel(const float* __restrict__ pred_boxes,   // [BQ,4] cxcywh
                 const int*   __restrict__ tgt_ids,      // [T] 1-based
                 const float* __restrict__ tgt_boxes,    // [T,4] cxcywh
                 const float* __restrict__ cd,           // [BQ,C] weighted
                 float*       __restrict__ out) {        // [BQ,T]
    __shared__ float  lds_cd[kTI * kC];   // 16 rows x 91 = 5824 B, contiguous in cd
    __shared__ float4 lds_pb[kTI];        // 16 pred boxes (raw cxcywh)

    const int tid = threadIdx.x;
    const int i0  = blockIdx.y * kTI;
    const int j0  = blockIdx.x * kJB + tid * kJT;
    const bool valid = (j0 + kJT <= kT);  // T%4==0 -> all-or-nothing per thread

    // Stage: cd rows i0..i0+15 are contiguous in memory -> coalesced copy
    for (int k = tid; k < kTI * kC; k += kBT)
        lds_cd[k] = cd[i0 * kC + k];
    if (tid < kTI)
        lds_pb[tid] = reinterpret_cast<const float4*>(pred_boxes)[i0 + tid];
    __syncthreads();

    // Per-thread target data: load + convert ONCE (reused across 16 i's)
    float tcx[kJT], tcy[kJT], tw[kJT], th[kJT];
    float tx0[kJT], ty0[kJT], tx1[kJT], ty1[kJT], ta[kJT];
    int   tco[kJT];
    if (valid) {
        int4 ids = *reinterpret_cast<const int4*>(&tgt_ids[j0]);
        tco[0] = ids.x - 1; tco[1] = ids.y - 1; tco[2] = ids.z - 1; tco[3] = ids.w - 1;
        #pragma unroll
        for (int q = 0; q < kJT; ++q) {
            float4 tb = reinterpret_cast<const float4*>(tgt_boxes)[j0 + q];
            tcx[q] = tb.x; tcy[q] = tb.y; tw[q] = tb.z; th[q] = tb.w;
            tx0[q] = tb.x - 0.5f * tb.z;  ty0[q] = tb.y - 0.5f * tb.w;
            tx1[q] = tb.x + 0.5f * tb.z;  ty1[q] = tb.y + 0.5f * tb.w;
            ta[q]  = tb.z * tb.w;
        }
    } else {
        #pragma unroll
        for (int q = 0; q < kJT; ++q) {
            tcx[q] = tcy[q] = tw[q] = th[q] = 0.f;
            tx0[q] = ty0[q] = tx1[q] = ty1[q] = ta[q] = 0.f;
            tco[q] = 0;
        }
    }

    for (int ii = 0; ii < kTI; ++ii) {
        const float4 pb = lds_pb[ii];     // broadcast ds_read_b128
        const float pcx = pb.x, pcy = pb.y, pw = pb.z, ph = pb.w;
        const float px0 = pcx - 0.5f * pw, py0 = pcy - 0.5f * ph;
        const float px1 = pcx + 0.5f * pw, py1 = pcy + 0.5f * ph;
        const float pa  = pw * ph;

        float4 res;
        #pragma unroll
        for (int q = 0; q < kJT; ++q) {
            float cdv = lds_cd[ii * kC + tco[q]];   // LDS gather, ~2-way banks

            float l1 = fabsf(pcx - tcx[q]) + fabsf(pcy - tcy[q])
                     + fabsf(pw  - tw[q] ) + fabsf(ph  - th[q] );

            float lx = fmaxf(px0, tx0[q]), ly = fmaxf(py0, ty0[q]);
            float rx = fminf(px1, tx1[q]), ry = fminf(py1, ty1[q]);
            float iw = fmaxf(rx - lx, 0.f), ih = fmaxf(ry - ly, 0.f);
            float inter = iw * ih;
            float uni   = pa + ta[q] - inter;
            float iou   = inter * __builtin_amdgcn_rcpf(fmaxf(uni, 1e-6f));

            float ex0 = fminf(px0, tx0[q]), ey0 = fminf(py0, ty0[q]);
            float ex1 = fmaxf(px1, tx1[q]), ey1 = fmaxf(py1, ty1[q]);
            float ew  = fmaxf(ex1 - ex0, 0.f), eh = fmaxf(ey1 - ey0, 0.f);
            float enc = ew * eh;
            float giou = iou - (enc - uni) * __builtin_amdgcn_rcpf(fmaxf(enc, 1e-6f));

            // cd carries W_CLASS=2; W_BBOX=5, W_GIOU=2 (cost uses -giou)
            float c = cdv + 5.0f * l1 - 2.0f * giou;
            (&res.x)[q] = c;
        }

        if (valid) {
            size_t off = (size_t)(i0 + ii) * kT + j0;
            *reinterpret_cast<float4*>(&out[off]) = res;   // global_store_dwordx4
        }
    }
}

extern "C" void kernel_launch(void* const* d_in, const int* in_sizes, int n_in,
                              void* d_out, int out_size, void* d_ws, size_t ws_size,
                              hipStream_t stream) {
    const float* logits  = (const float*)d_in[0];   // [16,900,91]
    const float* pboxes  = (const float*)d_in[1];   // [16,900,4]
    const int*   tids    = (const int*)d_in[2];     // [4800]
    const float* tboxes  = (const float*)d_in[3];   // [4800,4]
    float* out = (float*)d_out;                     // [16,900,4800]
    float* cd  = (float*)d_ws;                      // [14400,91] = 5.24 MB

    const int n_cd = kBQ * kC;
    class_cost_kernel<<<(n_cd + 255) / 256, 256, 0, stream>>>(logits, cd, n_cd);

    dim3 grid((kT + kJB - 1) / kJB, kBQ / kTI);     // (5, 900)
    cost_kernel<<<grid, 256, 0, stream>>>(pboxes, tids, tboxes, cd, out);
}